// Round 1
// baseline (463.517 us; speedup 1.0000x reference)
//
#include <hip/hip_runtime.h>
#include <stdint.h>

typedef float    f32x4  __attribute__((ext_vector_type(4)));
typedef float    f32x4v __attribute__((ext_vector_type(4)));
typedef __bf16   bf16x8 __attribute__((ext_vector_type(8)));
typedef unsigned int u32x4 __attribute__((ext_vector_type(4)));
typedef unsigned short ushort_t;

#define NB     65536   // batch
#define BM     128     // rows per block
#define NSTRIP 128     // n-cols per block (per gate)
#define BK     32
#define NSTEPS 40      // 1280 / 32

// LDS byte-region bases (total exactly 65536 B)
#define A_HI 0
#define A_LO 8192
#define B_HI 16384
#define B_LO 40960

union Frag8 { ushort_t u[8]; u32x4 q; bf16x8 v; };

static __device__ __forceinline__ ushort_t bf16_rne(float x) {
  uint32_t u = __float_as_uint(x);
  u += 0x7FFFu + ((u >> 16) & 1u);
  return (ushort_t)(u >> 16);
}
static __device__ __forceinline__ float bf16_f(ushort_t h) {
  return __uint_as_float(((uint32_t)h) << 16);
}

__global__ __launch_bounds__(512, 2)
void treelstm_fused(const float* __restrict__ inputs,
                    const float* __restrict__ children,
                    const float* __restrict__ Wi, const float* __restrict__ bi,
                    const float* __restrict__ Wo, const float* __restrict__ bo,
                    const float* __restrict__ Wu, const float* __restrict__ bu,
                    const float* __restrict__ Ui, const float* __restrict__ Uo,
                    const float* __restrict__ Uu,
                    float* __restrict__ out)
{
  __shared__ u32x4 lds_u4[4096];           // 65536 B
  char* lds = (char*)lds_u4;

  const int tid = threadIdx.x;
  const int bid = blockIdx.x;
  // XCD-aware bijective swizzle (1024 blocks = 8 * 128)
  const int wg     = (bid & 7) * 128 + (bid >> 3);
  const int strip  = wg >> 9;              // 0..1  (n-strip)
  const int rowblk = wg & 511;             // 0..511
  const int b0 = rowblk * BM;
  const int n0 = strip * NSTRIP;

  // staging decomposition: thread -> (row, k-chunk of 8)
  const int rowA = tid >> 2;               // 0..127
  const int koff = (tid & 3) * 8;          // 0,8,16,24

  const float* Wg[3] = {Wi, Wo, Wu};
  const float* Ug[3] = {Ui, Uo, Uu};

  // wave decomposition: 8 waves as 2 (rows) x 4 (cols); wave tile 64 x (32n x 3g)
  const int lane = tid & 63;
  const int wid  = tid >> 6;
  const int wr   = wid >> 2;               // 0..1
  const int wc   = wid & 3;                // 0..3
  const int lc   = lane & 15;              // row/col within 16x16 frag
  const int qq   = lane >> 4;              // k-chunk selector (0..3)

  f32x4 acc[4][2][3];                      // [rf][cf][gate]
  #pragma unroll
  for (int a = 0; a < 4; ++a)
    #pragma unroll
    for (int b = 0; b < 2; ++b)
      #pragma unroll
      for (int g = 0; g < 3; ++g)
        acc[a][b][g] = (f32x4){0.f, 0.f, 0.f, 0.f};

  float va[8];
  float vb[3][8];

  auto loadStep = [&](int s) {
    const int k0 = s * BK;
    const float* pa;
    if (s < 8) {
      pa = inputs + (size_t)(b0 + rowA) * 256 + (k0 + koff);
    } else {
      const int kc = (s - 8) >> 3;
      const int m0 = ((s - 8) & 7) * BK;
      pa = children + ((size_t)kc * NB + (size_t)(b0 + rowA)) * 512 + (m0 + koff);
    }
    f32x4v t0 = *(const f32x4v*)pa;
    f32x4v t1 = *(const f32x4v*)(pa + 4);
    #pragma unroll
    for (int j = 0; j < 4; ++j) { va[j] = t0[j]; va[4 + j] = t1[j]; }
    #pragma unroll
    for (int g = 0; g < 3; ++g) {
      const float* pb;
      if (s < 8) {
        pb = Wg[g] + (size_t)(n0 + rowA) * 256 + (k0 + koff);
      } else {
        const int kc = (s - 8) >> 3;
        const int m0 = ((s - 8) & 7) * BK;
        pb = Ug[g] + (size_t)kc * 65536 + (size_t)(n0 + rowA) * 256 + (m0 + koff);
      }
      f32x4v u0 = *(const f32x4v*)pb;
      f32x4v u1 = *(const f32x4v*)(pb + 4);
      #pragma unroll
      for (int j = 0; j < 4; ++j) { vb[g][j] = u0[j]; vb[g][4 + j] = u1[j]; }
    }
  };

  auto storeStep = [&]() {
    Frag8 h, l;
    #pragma unroll
    for (int j = 0; j < 8; ++j) {
      ushort_t hb = bf16_rne(va[j]);
      h.u[j] = hb;
      l.u[j] = bf16_rne(va[j] - bf16_f(hb));
    }
    *(u32x4*)(lds + A_HI + rowA * 64 + koff * 2) = h.q;
    *(u32x4*)(lds + A_LO + rowA * 64 + koff * 2) = l.q;
    #pragma unroll
    for (int g = 0; g < 3; ++g) {
      Frag8 hg, lg;
      #pragma unroll
      for (int j = 0; j < 8; ++j) {
        ushort_t hb = bf16_rne(vb[g][j]);
        hg.u[j] = hb;
        lg.u[j] = bf16_rne(vb[g][j] - bf16_f(hb));
      }
      *(u32x4*)(lds + B_HI + (g * 128 + rowA) * 64 + koff * 2) = hg.q;
      *(u32x4*)(lds + B_LO + (g * 128 + rowA) * 64 + koff * 2) = lg.q;
    }
  };

  auto computeStep = [&]() {
    Frag8 ah[4], al[4];
    #pragma unroll
    for (int rf = 0; rf < 4; ++rf) {
      const int row = wr * 64 + rf * 16 + lc;
      ah[rf].q = *(const u32x4*)(lds + A_HI + row * 64 + qq * 16);
      al[rf].q = *(const u32x4*)(lds + A_LO + row * 64 + qq * 16);
    }
    #pragma unroll
    for (int g = 0; g < 3; ++g) {
      #pragma unroll
      for (int cf = 0; cf < 2; ++cf) {
        const int col = wc * 32 + cf * 16 + lc;
        Frag8 bh, bl;
        bh.q = *(const u32x4*)(lds + B_HI + (g * 128 + col) * 64 + qq * 16);
        bl.q = *(const u32x4*)(lds + B_LO + (g * 128 + col) * 64 + qq * 16);
        #pragma unroll
        for (int rf = 0; rf < 4; ++rf) {
          acc[rf][cf][g] = __builtin_amdgcn_mfma_f32_16x16x32_bf16(ah[rf].v, bh.v, acc[rf][cf][g], 0, 0, 0);
          acc[rf][cf][g] = __builtin_amdgcn_mfma_f32_16x16x32_bf16(al[rf].v, bh.v, acc[rf][cf][g], 0, 0, 0);
          acc[rf][cf][g] = __builtin_amdgcn_mfma_f32_16x16x32_bf16(ah[rf].v, bl.v, acc[rf][cf][g], 0, 0, 0);
        }
      }
    }
  };

  loadStep(0);
  #pragma unroll 1
  for (int s = 0; s < NSTEPS; ++s) {
    if (s) __syncthreads();      // readers of previous tile done
    storeStep();
    __syncthreads();             // tile ready
    if (s + 1 < NSTEPS) loadStep(s + 1);   // prefetch next (hides under MFMA)
    computeStep();
  }

  // ---- epilogue: i,o,u -> (h, c) ----
  #pragma unroll
  for (int cf = 0; cf < 2; ++cf) {
    const int n = n0 + wc * 32 + cf * 16 + lc;
    const float bin = bi[n], bon = bo[n], bun = bu[n];
    #pragma unroll
    for (int rf = 0; rf < 4; ++rf) {
      const int brow = b0 + wr * 64 + rf * 16 + qq * 4;
      #pragma unroll
      for (int r = 0; r < 4; ++r) {
        const float iv = acc[rf][cf][0][r] + bin;
        const float ov = acc[rf][cf][1][r] + bon;
        const float uv = acc[rf][cf][2][r] + bun;
        const float tu = 1.f - 2.f / (1.f + __expf(2.f * uv));
        const float si = 1.f / (1.f + __expf(-iv));
        const float cv = si * tu;
        const float so = 1.f / (1.f + __expf(-ov));
        const float tc = 1.f - 2.f / (1.f + __expf(2.f * cv));
        const float hv = so * tc;
        const size_t base = (size_t)(brow + r) * 512 + (size_t)n;
        out[base]       = hv;
        out[base + 256] = cv;
      }
    }
  }
}

extern "C" void kernel_launch(void* const* d_in, const int* in_sizes, int n_in,
                              void* d_out, int out_size, void* d_ws, size_t ws_size,
                              hipStream_t stream) {
  const float* inputs   = (const float*)d_in[0];
  const float* children = (const float*)d_in[1];
  // d_in[2] = arities (unused by reference)
  const float* Wi = (const float*)d_in[3];
  const float* bi = (const float*)d_in[4];
  const float* Wo = (const float*)d_in[5];
  const float* bo = (const float*)d_in[6];
  const float* Wu = (const float*)d_in[7];
  const float* bu = (const float*)d_in[8];
  // d_in[9]=Wf, d_in[10]=bf (unused)
  const float* Ui = (const float*)d_in[11];
  const float* Uo = (const float*)d_in[12];
  const float* Uu = (const float*)d_in[13];
  // d_in[14]=Uf (unused)
  float* out = (float*)d_out;

  dim3 grid(1024), block(512);
  hipLaunchKernelGGL(treelstm_fused, grid, block, 0, stream,
                     inputs, children, Wi, bi, Wo, bo, Wu, bu, Ui, Uo, Uu, out);
}

// Round 2
// 400.950 us; speedup vs baseline: 1.1560x; 1.1560x over previous
//
#include <hip/hip_runtime.h>
#include <stdint.h>

typedef float    f32x4  __attribute__((ext_vector_type(4)));
typedef __bf16   bf16x8 __attribute__((ext_vector_type(8)));
typedef unsigned int u32x4 __attribute__((ext_vector_type(4)));
typedef unsigned short ushort_t;

#define NB     65536   // batch
#define BM     128     // rows per block
#define BK     32
#define NSTEPS 40      // 1280 / 32

// ---- dynamic LDS layout (bytes) for v2 kernel ----
// A:  128 rows x 128 B (hi chunks 0-3 | lo chunks 4-7, XOR-swizzled c^(row&7))
// B:  two buffers, each [3 gates][128 n][128 B] same row format
#define LDS_A     0
#define LDS_B0    16384
#define LDS_B1    65536
#define LDS_TOTAL 114688

// ws layout: [kt 0..39][g 0..2][n 0..255][128 B row], row = swizzled hi/lo image
#define WS_B_BYTES (40ull * 3ull * 256ull * 128ull)   // 3,932,160

union Frag8 { ushort_t u[8]; u32x4 q; bf16x8 v; };

static __device__ __forceinline__ ushort_t bf16_rne(float x) {
  uint32_t u = __float_as_uint(x);
  u += 0x7FFFu + ((u >> 16) & 1u);
  return (ushort_t)(u >> 16);
}
static __device__ __forceinline__ float bf16_f(ushort_t h) {
  return __uint_as_float(((uint32_t)h) << 16);
}

typedef const __attribute__((address_space(1))) void gas_void;
typedef __attribute__((address_space(3))) void las_void;

static __device__ __forceinline__ void glds16(const void* g, void* l) {
  __builtin_amdgcn_global_load_lds((gas_void*)g, (las_void*)l, 16, 0, 0);
}

// ============================ prep: pack weights ============================
__global__ __launch_bounds__(256)
void prep_weights(const float* __restrict__ Wi, const float* __restrict__ Wo,
                  const float* __restrict__ Wu,
                  const float* __restrict__ Ui, const float* __restrict__ Uo,
                  const float* __restrict__ Uu,
                  char* __restrict__ wsB)
{
  const int idx = blockIdx.x * 256 + threadIdx.x;   // 40*3*256*4 = 122880
  const int qq = idx & 3;
  const int n  = (idx >> 2) & 255;
  const int t  = idx >> 10;        // kt*3 + g, 0..119 (uniform per block)
  const int g  = t % 3;
  const int kt = t / 3;
  const float* Wg = (g == 0) ? Wi : (g == 1) ? Wo : Wu;
  const float* Ug = (g == 0) ? Ui : (g == 1) ? Uo : Uu;
  const int k0 = kt * 32 + qq * 8;
  const float* src;
  if (k0 < 256) {
    src = Wg + (size_t)n * 256 + k0;
  } else {
    const int kc = (k0 - 256) >> 8;
    const int m  = (k0 - 256) & 255;
    src = Ug + (size_t)kc * 65536 + (size_t)n * 256 + m;
  }
  f32x4 a = *(const f32x4*)src;
  f32x4 b = *(const f32x4*)(src + 4);
  Frag8 hi, lo;
  #pragma unroll
  for (int j = 0; j < 4; ++j) {
    ushort_t h0 = bf16_rne(a[j]);
    hi.u[j] = h0; lo.u[j] = bf16_rne(a[j] - bf16_f(h0));
    ushort_t h1 = bf16_rne(b[j]);
    hi.u[4 + j] = h1; lo.u[4 + j] = bf16_rne(b[j] - bf16_f(h1));
  }
  char* base = wsB + ((size_t)t * 256 + n) * 128;
  const int sw = n & 7;
  *(u32x4*)(base + ((qq ^ sw) << 4))       = hi.q;
  *(u32x4*)(base + (((qq | 4) ^ sw) << 4)) = lo.q;
}

// ============================ v2 main kernel ============================
__global__ __launch_bounds__(512, 2)
void treelstm_fused_v2(const float* __restrict__ inputs,
                       const float* __restrict__ children,
                       const char*  __restrict__ wsB,
                       const float* __restrict__ bi, const float* __restrict__ bo,
                       const float* __restrict__ bu,
                       float* __restrict__ out)
{
  extern __shared__ __align__(16) char lds[];

  const int tid = threadIdx.x;
  const int bid = blockIdx.x;
  // XCD-aware bijective swizzle (1024 blocks = 8 * 128)
  const int wg     = (bid & 7) * 128 + (bid >> 3);
  const int strip  = wg >> 9;
  const int rowblk = wg & 511;
  const int b0 = rowblk * BM;
  const int n0 = strip * 128;

  const int rowA = tid >> 2;       // 0..127
  const int ca   = tid & 3;        // A k-chunk 0..3
  const int lane = tid & 63;
  const int wid  = tid >> 6;
  const int wr   = wid >> 2;       // 0..1
  const int wc   = wid & 3;        // 0..3
  const int lc   = lane & 15;
  const int qq   = lane >> 4;      // 0..3

  f32x4 acc[4][2][3];
  #pragma unroll
  for (int a = 0; a < 4; ++a)
    #pragma unroll
    for (int b = 0; b < 2; ++b)
      #pragma unroll
      for (int g = 0; g < 3; ++g)
        acc[a][b][g] = (f32x4){0.f, 0.f, 0.f, 0.f};

  auto aPtr = [&](int s) -> const float* {
    if (s < 8) return inputs + (size_t)(b0 + rowA) * 256 + s * 32 + ca * 8;
    const int ss = s - 8;
    const int kc = ss >> 3;
    const int m0 = (ss & 7) * 32;
    return children + ((size_t)kc * NB + (size_t)(b0 + rowA)) * 512 + m0 + ca * 8;
  };

  auto writeA = [&](const f32x4& x, const f32x4& y) {
    Frag8 hi, lo;
    #pragma unroll
    for (int j = 0; j < 4; ++j) {
      ushort_t h0 = bf16_rne(x[j]);
      hi.u[j] = h0; lo.u[j] = bf16_rne(x[j] - bf16_f(h0));
      ushort_t h1 = bf16_rne(y[j]);
      hi.u[4 + j] = h1; lo.u[4 + j] = bf16_rne(y[j] - bf16_f(h1));
    }
    char* base = lds + LDS_A + rowA * 128;
    const int sw = rowA & 7;
    *(u32x4*)(base + ((ca ^ sw) << 4))       = hi.q;
    *(u32x4*)(base + (((ca | 4) ^ sw) << 4)) = lo.q;
  };

  auto stageB = [&](int s, int bufoff) {
    const char* gbase = wsB + (size_t)s * 98304 + (size_t)n0 * 128;
    #pragma unroll
    for (int g = 0; g < 3; ++g) {
      const char* gp = gbase + g * 32768;
      char* lp = lds + bufoff + g * 16384 + wid * 1024;
      glds16(gp + wid * 1024 + lane * 16, lp);
      glds16(gp + 8192 + wid * 1024 + lane * 16, lp + 8192);
    }
  };

  auto computeStep = [&](int bufoff) {
    Frag8 ah[4], al[4];
    #pragma unroll
    for (int rf = 0; rf < 4; ++rf) {
      const int row = wr * 64 + rf * 16 + lc;
      const char* p = lds + LDS_A + row * 128;
      const int sw = row & 7;
      ah[rf].q = *(const u32x4*)(p + ((qq ^ sw) << 4));
      al[rf].q = *(const u32x4*)(p + (((qq | 4) ^ sw) << 4));
    }
    #pragma unroll
    for (int g = 0; g < 3; ++g) {
      #pragma unroll
      for (int cf = 0; cf < 2; ++cf) {
        const int col = wc * 32 + cf * 16 + lc;
        const char* p = lds + bufoff + g * 16384 + col * 128;
        const int sw = col & 7;
        Frag8 bh, bl;
        bh.q = *(const u32x4*)(p + ((qq ^ sw) << 4));
        bl.q = *(const u32x4*)(p + (((qq | 4) ^ sw) << 4));
        #pragma unroll
        for (int rf = 0; rf < 4; ++rf) {
          acc[rf][cf][g] = __builtin_amdgcn_mfma_f32_16x16x32_bf16(ah[rf].v, bh.v, acc[rf][cf][g], 0, 0, 0);
          acc[rf][cf][g] = __builtin_amdgcn_mfma_f32_16x16x32_bf16(al[rf].v, bh.v, acc[rf][cf][g], 0, 0, 0);
          acc[rf][cf][g] = __builtin_amdgcn_mfma_f32_16x16x32_bf16(ah[rf].v, bl.v, acc[rf][cf][g], 0, 0, 0);
        }
      }
    }
  };

  // counted-vmcnt barrier: B(s) done (6 oldest), 8 newer (2 A + 6 glds) in flight
  #define PRE_BARRIER_8() asm volatile("s_waitcnt vmcnt(8) lgkmcnt(0)\n\ts_barrier" ::: "memory")
  #define PRE_BARRIER_0() asm volatile("s_waitcnt vmcnt(0) lgkmcnt(0)\n\ts_barrier" ::: "memory")
  #define POST_BARRIER() do { __builtin_amdgcn_sched_barrier(0); \
    asm volatile("s_waitcnt lgkmcnt(0)\n\ts_barrier" ::: "memory"); } while (0)

  // prologue
  f32x4 xa, ya, xb, yb;
  { const float* p = aPtr(0); xa = *(const f32x4*)p; ya = *(const f32x4*)(p + 4); }
  stageB(0, LDS_B0);

  #pragma unroll 1
  for (int t = 0; t < 20; ++t) {
    const int s0 = 2 * t;
    // ---- phase A: compute step s0 from B0 ----
    writeA(xa, ya);                                   // waits A(s0) regs only (vmcnt auto)
    { const float* p = aPtr(s0 + 1); xb = *(const f32x4*)p; yb = *(const f32x4*)(p + 4); }
    stageB(s0 + 1, LDS_B1);
    PRE_BARRIER_8();
    computeStep(LDS_B0);
    POST_BARRIER();
    // ---- phase B: compute step s0+1 from B1 ----
    writeA(xb, yb);
    if (t < 19) {
      const float* p = aPtr(s0 + 2); xa = *(const f32x4*)p; ya = *(const f32x4*)(p + 4);
      stageB(s0 + 2, LDS_B0);
      PRE_BARRIER_8();
    } else {
      PRE_BARRIER_0();
    }
    computeStep(LDS_B1);
    POST_BARRIER();
  }

  // ---- epilogue ----
  #pragma unroll
  for (int cf = 0; cf < 2; ++cf) {
    const int n = n0 + wc * 32 + cf * 16 + lc;
    const float bin = bi[n], bon = bo[n], bun = bu[n];
    #pragma unroll
    for (int rf = 0; rf < 4; ++rf) {
      const int brow = b0 + wr * 64 + rf * 16 + qq * 4;
      #pragma unroll
      for (int r = 0; r < 4; ++r) {
        const float iv = acc[rf][cf][0][r] + bin;
        const float ov = acc[rf][cf][1][r] + bon;
        const float uv = acc[rf][cf][2][r] + bun;
        const float tu = 1.f - 2.f / (1.f + __expf(2.f * uv));
        const float si = 1.f / (1.f + __expf(-iv));
        const float cv = si * tu;
        const float so = 1.f / (1.f + __expf(-ov));
        const float tc = 1.f - 2.f / (1.f + __expf(2.f * cv));
        const float hv = so * tc;
        const size_t base = (size_t)(brow + r) * 512 + (size_t)n;
        out[base]       = hv;
        out[base + 256] = cv;
      }
    }
  }
}

// ================= v1 fallback (ws too small): R1 kernel =================
#define A_HI 0
#define A_LO 8192
#define B_HI 16384
#define B_LO 40960

__global__ __launch_bounds__(512, 2)
void treelstm_fused_v1(const float* __restrict__ inputs,
                       const float* __restrict__ children,
                       const float* __restrict__ Wi, const float* __restrict__ bi,
                       const float* __restrict__ Wo, const float* __restrict__ bo,
                       const float* __restrict__ Wu, const float* __restrict__ bu,
                       const float* __restrict__ Ui, const float* __restrict__ Uo,
                       const float* __restrict__ Uu,
                       float* __restrict__ out)
{
  __shared__ u32x4 lds_u4[4096];
  char* lds = (char*)lds_u4;
  const int tid = threadIdx.x;
  const int bid = blockIdx.x;
  const int wg     = (bid & 7) * 128 + (bid >> 3);
  const int strip  = wg >> 9;
  const int rowblk = wg & 511;
  const int b0 = rowblk * BM;
  const int n0 = strip * 128;
  const int rowA = tid >> 2;
  const int koff = (tid & 3) * 8;
  const float* Wg[3] = {Wi, Wo, Wu};
  const float* Ug[3] = {Ui, Uo, Uu};
  const int lane = tid & 63;
  const int wid  = tid >> 6;
  const int wr   = wid >> 2;
  const int wc   = wid & 3;
  const int lc   = lane & 15;
  const int qq   = lane >> 4;

  f32x4 acc[4][2][3];
  #pragma unroll
  for (int a = 0; a < 4; ++a)
    #pragma unroll
    for (int b = 0; b < 2; ++b)
      #pragma unroll
      for (int g = 0; g < 3; ++g)
        acc[a][b][g] = (f32x4){0.f, 0.f, 0.f, 0.f};

  float va[8];
  float vb[3][8];

  auto loadStep = [&](int s) {
    const int k0 = s * BK;
    const float* pa;
    if (s < 8) pa = inputs + (size_t)(b0 + rowA) * 256 + (k0 + koff);
    else {
      const int kc = (s - 8) >> 3;
      const int m0 = ((s - 8) & 7) * BK;
      pa = children + ((size_t)kc * NB + (size_t)(b0 + rowA)) * 512 + (m0 + koff);
    }
    f32x4 t0 = *(const f32x4*)pa;
    f32x4 t1 = *(const f32x4*)(pa + 4);
    #pragma unroll
    for (int j = 0; j < 4; ++j) { va[j] = t0[j]; va[4 + j] = t1[j]; }
    #pragma unroll
    for (int g = 0; g < 3; ++g) {
      const float* pb;
      if (s < 8) pb = Wg[g] + (size_t)(n0 + rowA) * 256 + (k0 + koff);
      else {
        const int kc = (s - 8) >> 3;
        const int m0 = ((s - 8) & 7) * BK;
        pb = Ug[g] + (size_t)kc * 65536 + (size_t)(n0 + rowA) * 256 + (m0 + koff);
      }
      f32x4 u0 = *(const f32x4*)pb;
      f32x4 u1 = *(const f32x4*)(pb + 4);
      #pragma unroll
      for (int j = 0; j < 4; ++j) { vb[g][j] = u0[j]; vb[g][4 + j] = u1[j]; }
    }
  };

  auto storeStep = [&]() {
    Frag8 h, l;
    #pragma unroll
    for (int j = 0; j < 8; ++j) {
      ushort_t hb = bf16_rne(va[j]);
      h.u[j] = hb;
      l.u[j] = bf16_rne(va[j] - bf16_f(hb));
    }
    *(u32x4*)(lds + A_HI + rowA * 64 + koff * 2) = h.q;
    *(u32x4*)(lds + A_LO + rowA * 64 + koff * 2) = l.q;
    #pragma unroll
    for (int g = 0; g < 3; ++g) {
      Frag8 hg, lg;
      #pragma unroll
      for (int j = 0; j < 8; ++j) {
        ushort_t hb = bf16_rne(vb[g][j]);
        hg.u[j] = hb;
        lg.u[j] = bf16_rne(vb[g][j] - bf16_f(hb));
      }
      *(u32x4*)(lds + B_HI + (g * 128 + rowA) * 64 + koff * 2) = hg.q;
      *(u32x4*)(lds + B_LO + (g * 128 + rowA) * 64 + koff * 2) = lg.q;
    }
  };

  auto computeStep = [&]() {
    Frag8 ah[4], al[4];
    #pragma unroll
    for (int rf = 0; rf < 4; ++rf) {
      const int row = wr * 64 + rf * 16 + lc;
      ah[rf].q = *(const u32x4*)(lds + A_HI + row * 64 + qq * 16);
      al[rf].q = *(const u32x4*)(lds + A_LO + row * 64 + qq * 16);
    }
    #pragma unroll
    for (int g = 0; g < 3; ++g) {
      #pragma unroll
      for (int cf = 0; cf < 2; ++cf) {
        const int col = wc * 32 + cf * 16 + lc;
        Frag8 bh, bl;
        bh.q = *(const u32x4*)(lds + B_HI + (g * 128 + col) * 64 + qq * 16);
        bl.q = *(const u32x4*)(lds + B_LO + (g * 128 + col) * 64 + qq * 16);
        #pragma unroll
        for (int rf = 0; rf < 4; ++rf) {
          acc[rf][cf][g] = __builtin_amdgcn_mfma_f32_16x16x32_bf16(ah[rf].v, bh.v, acc[rf][cf][g], 0, 0, 0);
          acc[rf][cf][g] = __builtin_amdgcn_mfma_f32_16x16x32_bf16(al[rf].v, bh.v, acc[rf][cf][g], 0, 0, 0);
          acc[rf][cf][g] = __builtin_amdgcn_mfma_f32_16x16x32_bf16(ah[rf].v, bl.v, acc[rf][cf][g], 0, 0, 0);
        }
      }
    }
  };

  loadStep(0);
  #pragma unroll 1
  for (int s = 0; s < NSTEPS; ++s) {
    if (s) __syncthreads();
    storeStep();
    __syncthreads();
    if (s + 1 < NSTEPS) loadStep(s + 1);
    computeStep();
  }

  #pragma unroll
  for (int cf = 0; cf < 2; ++cf) {
    const int n = n0 + wc * 32 + cf * 16 + lc;
    const float bin = bi[n], bon = bo[n], bun = bu[n];
    #pragma unroll
    for (int rf = 0; rf < 4; ++rf) {
      const int brow = b0 + wr * 64 + rf * 16 + qq * 4;
      #pragma unroll
      for (int r = 0; r < 4; ++r) {
        const float iv = acc[rf][cf][0][r] + bin;
        const float ov = acc[rf][cf][1][r] + bon;
        const float uv = acc[rf][cf][2][r] + bun;
        const float tu = 1.f - 2.f / (1.f + __expf(2.f * uv));
        const float si = 1.f / (1.f + __expf(-iv));
        const float cv = si * tu;
        const float so = 1.f / (1.f + __expf(-ov));
        const float tc = 1.f - 2.f / (1.f + __expf(2.f * cv));
        const float hv = so * tc;
        const size_t base = (size_t)(brow + r) * 512 + (size_t)n;
        out[base]       = hv;
        out[base + 256] = cv;
      }
    }
  }
}

extern "C" void kernel_launch(void* const* d_in, const int* in_sizes, int n_in,
                              void* d_out, int out_size, void* d_ws, size_t ws_size,
                              hipStream_t stream) {
  const float* inputs   = (const float*)d_in[0];
  const float* children = (const float*)d_in[1];
  const float* Wi = (const float*)d_in[3];
  const float* bi = (const float*)d_in[4];
  const float* Wo = (const float*)d_in[5];
  const float* bo = (const float*)d_in[6];
  const float* Wu = (const float*)d_in[7];
  const float* bu = (const float*)d_in[8];
  const float* Ui = (const float*)d_in[11];
  const float* Uo = (const float*)d_in[12];
  const float* Uu = (const float*)d_in[13];
  float* out = (float*)d_out;

  if (ws_size >= WS_B_BYTES) {
    char* wsB = (char*)d_ws;
    (void)hipFuncSetAttribute((const void*)treelstm_fused_v2,
                              hipFuncAttributeMaxDynamicSharedMemorySize, LDS_TOTAL);
    hipLaunchKernelGGL(prep_weights, dim3(480), dim3(256), 0, stream,
                       Wi, Wo, Wu, Ui, Uo, Uu, wsB);
    hipLaunchKernelGGL(treelstm_fused_v2, dim3(1024), dim3(512), LDS_TOTAL, stream,
                       inputs, children, wsB, bi, bo, bu, out);
  } else {
    hipLaunchKernelGGL(treelstm_fused_v1, dim3(1024), dim3(512), 0, stream,
                       inputs, children, Wi, bi, Wo, bo, Wu, bu, Ui, Uo, Uu, out);
  }
}